// Round 11
// baseline (706.335 us; speedup 1.0000x reference)
//
#include <hip/hip_runtime.h>
#include <hip/hip_bf16.h>

#define N_VOCAB 50257
#define NBC     786     // n-block columns (64 wide)
#define N_PAD   50304   // 786 * 64
#define D_K     1024
#define M_ROWS  2048
#define MT      32                  // m-tiles (2048/64)
#define GEMM_BLOCKS (NBC * MT)      // 25152 = 8 * 3144
#define PER_XCD     (GEMM_BLOCKS/8) // 3144

typedef __attribute__((ext_vector_type(4))) int i32x4;

__device__ inline signed char qint(float v, float s) {
  float q = fminf(fmaxf(rintf(v / s), -8.f), 7.f);
  return (signed char)(int)q;
}

// ---------------- fused absmax (x -> amax[0], W -> amax[1]) ----------------
__global__ void absmax2_kernel(const float4* __restrict__ x, int nx4,
                               const float4* __restrict__ Wp, int nw4,
                               unsigned* __restrict__ amax) {
  const bool isx = blockIdx.x < 512;
  const float4* p = isx ? x : Wp;
  const int n4 = isx ? nx4 : nw4;
  const int b0 = isx ? blockIdx.x : blockIdx.x - 512;
  const int nb = isx ? 512 : (gridDim.x - 512);
  float m = 0.f;
  for (int i = b0 * blockDim.x + threadIdx.x; i < n4; i += nb * blockDim.x) {
    float4 v = p[i];
    m = fmaxf(m, fmaxf(fmaxf(fabsf(v.x), fabsf(v.y)),
                       fmaxf(fabsf(v.z), fabsf(v.w))));
  }
#pragma unroll
  for (int off = 32; off; off >>= 1) m = fmaxf(m, __shfl_xor(m, off));
  __shared__ float red[4];
  int tid = threadIdx.x;
  if ((tid & 63) == 0) red[tid >> 6] = m;
  __syncthreads();
  if (tid == 0) {
    m = fmaxf(fmaxf(red[0], red[1]), fmaxf(red[2], red[3]));
    atomicMax(&amax[isx ? 0 : 1], __float_as_uint(m));
  }
}

// ---------------- fused quantize x, W, bias ----------------
__global__ void quant_kernel(const float4* __restrict__ x,
                             const float4* __restrict__ Wp,
                             const float* __restrict__ b,
                             char4* __restrict__ qx, char4* __restrict__ qw,
                             float* __restrict__ bq,
                             const unsigned* __restrict__ amax) {
  const int bid = blockIdx.x;
  const int tid = threadIdx.x;
  const int nw4 = (N_VOCAB * D_K) / 4;
  if (bid < 2048) {
    int i = bid * 256 + tid;
    float s = __uint_as_float(amax[0]) * (1.0f / 7.0f);
    float4 v = x[i];
    char4 q;
    q.x = qint(v.x, s); q.y = qint(v.y, s);
    q.z = qint(v.z, s); q.w = qint(v.w, s);
    qx[i] = q;
  } else if (bid < 2048 + 50304) {
    int i = (bid - 2048) * 256 + tid;
    char4 q = {0, 0, 0, 0};
    if (i < nw4) {
      float s = __uint_as_float(amax[1]) * (1.0f / 7.0f);
      float4 v = Wp[i];
      q.x = qint(v.x, s); q.y = qint(v.y, s);
      q.z = qint(v.z, s); q.w = qint(v.w, s);
    }
    qw[i] = q;
  } else {
    int i = (bid - (2048 + 50304)) * 256 + tid;
    if (i < N_PAD) {
      float v = 0.f;
      if (i < N_VOCAB) {
        float sb = (__uint_as_float(amax[0]) * (1.0f / 7.0f)) *
                   (__uint_as_float(amax[1]) * (1.0f / 7.0f));
        v = rintf(b[i] / sb) * sb;
      }
      bq[i] = v;
    }
  }
}

// ---------------- int8 GEMM: 1-wave 64x64, NO LDS, reg-direct frags ------
// Each block = ONE wave, 64x64 tile, acc 4x4. MFMA fragments are loaded
// DIRECTLY global->register: one global_load_dwordx4 covers 16 rows x 64
// contiguous bytes (perfect 64B sectors) - LDS would add a pure roundtrip
// since a 1-wave tile has no cross-wave reuse. Double-buffered named frag
// sets, full unroll (static indexing), NO barriers / NO manual waitcnt:
// with no barrier to force a drain, the compiler's dependence-based
// s_waitcnt vmcnt(N) is exactly the counted-vmcnt pipeline. ~3 waves/SIMD
// (VGPR-capped), all independent. XCD-bijective grid: 32 m-blocks of one
// column share its 64KB B panel in-XCD (L2). mfma_i32_16x16x64_i8.
__global__ __launch_bounds__(64, 3) void gemm_kernel(
    const signed char* __restrict__ qx,   // [2048][1024]
    const signed char* __restrict__ qw,   // [50304][1024]
    const float* __restrict__ bq,         // [50304]
    const unsigned* __restrict__ amax,
    float* __restrict__ outp,             // [2048][50257]
    float* __restrict__ pmax,             // [2048][NBC]
    float* __restrict__ psum)             // [2048][NBC]
{
  constexpr int BK = 64;
  constexpr int NT = D_K / BK;  // 16
  const int l = threadIdx.x & 63;

  const int bid = blockIdx.x;
  const int vb = (bid & 7) * PER_XCD + (bid >> 3);
  const int nb = vb >> 5;          // 0..785 (column tile)
  const int m0 = (vb & 31) * 64;   // m tile
  const int n0 = nb * 64;

  // per-lane fragment base: row = (l&15), k-slot byte = (l>>4)*16
  const signed char* pa = qx + (size_t)(m0 + (l & 15)) * D_K + (l >> 4) * 16;
  const signed char* pb = qw + (size_t)(n0 + (l & 15)) * D_K + (l >> 4) * 16;

  i32x4 acc[4][4] = {};
  i32x4 fa[2][4], fb[2][4];  // indexed by compile-time constants only

  // prologue: sets for k-tiles 0 and 1 in flight
#pragma unroll
  for (int i = 0; i < 4; ++i) {
    fa[0][i] = *(const i32x4*)(pa + i * (16 * D_K));
    fb[0][i] = *(const i32x4*)(pb + i * (16 * D_K));
  }
#pragma unroll
  for (int i = 0; i < 4; ++i) {
    fa[1][i] = *(const i32x4*)(pa + i * (16 * D_K) + BK);
    fb[1][i] = *(const i32x4*)(pb + i * (16 * D_K) + BK);
  }

#pragma unroll
  for (int kt = 0; kt < NT; ++kt) {
    const int s = kt & 1;  // compile-time constant under full unroll

    __builtin_amdgcn_s_setprio(1);
#pragma unroll
    for (int mi = 0; mi < 4; ++mi)
#pragma unroll
      for (int ni = 0; ni < 4; ++ni)
        acc[mi][ni] = __builtin_amdgcn_mfma_i32_16x16x64_i8(
            fa[s][mi], fb[s][ni], acc[mi][ni], 0, 0, 0);
    __builtin_amdgcn_s_setprio(0);

    // refill this set for k-tile kt+2 (WAR safe: MFMAs already issued)
    if (kt + 2 < NT) {
#pragma unroll
      for (int i = 0; i < 4; ++i) {
        fa[s][i] = *(const i32x4*)(pa + i * (16 * D_K) + (kt + 2) * BK);
        fb[s][i] = *(const i32x4*)(pb + i * (16 * D_K) + (kt + 2) * BK);
      }
    }
  }

  // ---- epilogue: scale + bias, softmax partials (pure shuffles) ----
  const float sx = __uint_as_float(amax[0]) * (1.0f / 7.0f);
  const float sw = __uint_as_float(amax[1]) * (1.0f / 7.0f);
  const float scale = sx * sw;

  bool valid[4];
  float bb[4];
#pragma unroll
  for (int ni = 0; ni < 4; ++ni) {
    int col = n0 + ni * 16 + (l & 15);
    valid[ni] = (col < N_VOCAB);
    bb[ni] = valid[ni] ? bq[col] : 0.f;
  }
  float lg[4][4][4];
#pragma unroll
  for (int mi = 0; mi < 4; ++mi)
#pragma unroll
    for (int ni = 0; ni < 4; ++ni)
#pragma unroll
      for (int r = 0; r < 4; ++r)
        lg[mi][ni][r] = (float)acc[mi][ni][r] * scale + bb[ni];

#pragma unroll
  for (int mi = 0; mi < 4; ++mi)
#pragma unroll
    for (int r = 0; r < 4; ++r) {
      float mval = -3.4e38f;
#pragma unroll
      for (int ni = 0; ni < 4; ++ni)
        if (valid[ni]) mval = fmaxf(mval, lg[mi][ni][r]);
#pragma unroll
      for (int off = 1; off < 16; off <<= 1)
        mval = fmaxf(mval, __shfl_xor(mval, off));
      float s = 0.f;
#pragma unroll
      for (int ni = 0; ni < 4; ++ni)
        if (valid[ni]) s += __expf(lg[mi][ni][r] - mval);
#pragma unroll
      for (int off = 1; off < 16; off <<= 1)
        s += __shfl_xor(s, off);
      if ((l & 15) == 0) {
        int rowg = m0 + mi * 16 + (l >> 4) * 4 + r;
        pmax[(size_t)rowg * NBC + nb] = mval;
        psum[(size_t)rowg * NBC + nb] = s;
      }
    }

  // ---- direct logit store, row-grouped ----
#pragma unroll
  for (int mi = 0; mi < 4; ++mi)
#pragma unroll
    for (int r = 0; r < 4; ++r) {
      int rowg = m0 + mi * 16 + (l >> 4) * 4 + r;
      size_t rb = (size_t)rowg * N_VOCAB;
#pragma unroll
      for (int ni = 0; ni < 4; ++ni) {
        if (valid[ni]) {
          int col = n0 + ni * 16 + (l & 15);
          outp[rb + col] = lg[mi][ni][r];
        }
      }
    }
}

// ---------------- merged: per-row logZ + subtract (2 blocks per row) --------
__global__ __launch_bounds__(256) void logz_sub_kernel(
    const float* __restrict__ pmax, const float* __restrict__ psum,
    float* __restrict__ out) {
  const int row = blockIdx.x >> 1;
  const int half = blockIdx.x & 1;
  const float* pm = pmax + (size_t)row * NBC;
  const float* ps = psum + (size_t)row * NBC;
  const int tid = threadIdx.x;
  __shared__ float red[9];

  float m = -3.4e38f;
  for (int i = tid; i < NBC; i += 256) m = fmaxf(m, pm[i]);
#pragma unroll
  for (int off = 32; off; off >>= 1) m = fmaxf(m, __shfl_xor(m, off));
  if ((tid & 63) == 0) red[tid >> 6] = m;
  __syncthreads();
  m = fmaxf(fmaxf(red[0], red[1]), fmaxf(red[2], red[3]));

  float s = 0.f;
  for (int i = tid; i < NBC; i += 256) s += ps[i] * __expf(pm[i] - m);
#pragma unroll
  for (int off = 32; off; off >>= 1) s += __shfl_xor(s, off);
  if ((tid & 63) == 0) red[4 + (tid >> 6)] = s;
  __syncthreads();
  if (tid == 0) {
    s = red[4] + red[5] + red[6] + red[7];
    red[8] = m + __logf(s);
  }
  __syncthreads();
  const float lz = red[8];

  // subtract in place; this block handles its half of the row
  const size_t base = (size_t)row * N_VOCAB;
  const int a = (4 - (row & 3)) & 3;  // head scalars to align to 16B
  const int n4 = (N_VOCAB - a) >> 2;  // aligned float4 count
  const int h4 = (n4 + 1) >> 1;       // per-half float4s
  const int i0 = half * h4;
  const int i1 = min(n4, i0 + h4);
  float4* p = (float4*)(out + base + a);
  for (int i = i0 + tid; i < i1; i += 256) {
    float4 v = p[i];
    v.x -= lz; v.y -= lz; v.z -= lz; v.w -= lz;
    p[i] = v;
  }
  if (half == 0) {
    if (tid < a) out[base + tid] -= lz;
  } else {
    const int done = a + n4 * 4;
    if (tid < N_VOCAB - done) out[base + done + tid] -= lz;
  }
}

extern "C" void kernel_launch(void* const* d_in, const int* in_sizes, int n_in,
                              void* d_out, int out_size, void* d_ws,
                              size_t ws_size, hipStream_t stream) {
  const float* x = (const float*)d_in[0];
  const float* W = (const float*)d_in[1];
  const float* b = (const float*)d_in[2];
  float* out = (float*)d_out;

  char* ws = (char*)d_ws;
  unsigned* amax = (unsigned*)ws;                        // 8 B
  float* bq = (float*)(ws + 4096);                       // 202 KB
  float* pmax = (float*)(ws + (1ull << 20));             // 6.44 MB
  float* psum = (float*)(ws + (8ull << 20));             // 6.44 MB
  signed char* qx = (signed char*)(ws + (15ull << 20));  // 2 MB
  signed char* qw = (signed char*)(ws + (17ull << 20));  // 51.5 MB

  hipMemsetAsync(amax, 0, 8, stream);

  const int nx4 = (M_ROWS * D_K) / 4;   // 524288
  const int nw4 = (N_VOCAB * D_K) / 4;  // 12865792

  absmax2_kernel<<<2560, 256, 0, stream>>>((const float4*)x, nx4,
                                           (const float4*)W, nw4, amax);

  quant_kernel<<<2048 + 50304 + 197, 256, 0, stream>>>(
      (const float4*)x, (const float4*)W, b, (char4*)qx, (char4*)qw, bq, amax);

  gemm_kernel<<<GEMM_BLOCKS, 64, 0, stream>>>(qx, qw, bq, amax, out, pmax,
                                              psum);

  logz_sub_kernel<<<M_ROWS * 2, 256, 0, stream>>>(pmax, psum, out);
}

// Round 12
// 617.566 us; speedup vs baseline: 1.1437x; 1.1437x over previous
//
#include <hip/hip_runtime.h>
#include <hip/hip_bf16.h>

#define N_VOCAB 50257
#define NB      393     // n-block columns
#define N_PAD   50304   // 393 * 128
#define D_K     1024
#define M_ROWS  2048
#define GEMM_BLOCKS (NB * 16)       // 6288 = 8 * 786
#define PER_XCD     (GEMM_BLOCKS/8) // 786

typedef __attribute__((ext_vector_type(4))) int i32x4;

__device__ inline void async_copy16(const void* g, void* l) {
  auto* gp = (const __attribute__((address_space(1))) unsigned int*)g;
  auto* lp = (__attribute__((address_space(3))) unsigned int*)l;
  __builtin_amdgcn_global_load_lds(gp, lp, 16, 0, 0);
}

__device__ inline unsigned long long q8(float v, float s) {
  float q = fminf(fmaxf(rintf(v / s), -8.f), 7.f);
  return (unsigned long long)(unsigned char)(signed char)(int)q;
}

// ---------------- fused absmax (x -> amax[0], W -> amax[1]) ----------------
__global__ __launch_bounds__(256) void absmax2_kernel(
    const float4* __restrict__ x, int nx4, const float4* __restrict__ Wp,
    int nw4, unsigned* __restrict__ amax) {
  const bool isx = blockIdx.x < 512;
  const float4* p = isx ? x : Wp;
  const int n4 = isx ? nx4 : nw4;
  const int b0 = isx ? blockIdx.x : blockIdx.x - 512;
  const int nb = isx ? 512 : (gridDim.x - 512);
  float m = 0.f;
  for (int i = b0 * blockDim.x + threadIdx.x; i < n4; i += nb * blockDim.x) {
    float4 v = p[i];
    m = fmaxf(m, fmaxf(fmaxf(fabsf(v.x), fabsf(v.y)),
                       fmaxf(fabsf(v.z), fabsf(v.w))));
  }
#pragma unroll
  for (int off = 32; off; off >>= 1) m = fmaxf(m, __shfl_xor(m, off));
  __shared__ float red[4];
  int tid = threadIdx.x;
  if ((tid & 63) == 0) red[tid >> 6] = m;
  __syncthreads();
  if (tid == 0) {
    m = fmaxf(fmaxf(red[0], red[1]), fmaxf(red[2], red[3]));
    atomicMax(&amax[isx ? 0 : 1], __float_as_uint(m));
  }
}

// ---------------- fused quantize x, W (8 elems/thread), bias ----------------
#define XB8  1024   // x blocks: 2048*1024/8/256
#define WB8  25152  // W blocks: 50304*1024/8/256
__global__ __launch_bounds__(256) void quant_kernel(
    const float4* __restrict__ x, const float4* __restrict__ Wp,
    const float* __restrict__ b, unsigned long long* __restrict__ qx,
    unsigned long long* __restrict__ qw, float* __restrict__ bq,
    const unsigned* __restrict__ amax) {
  const int bid = blockIdx.x;
  const int tid = threadIdx.x;
  if (bid < XB8) {
    int i = bid * 256 + tid;
    float s = __uint_as_float(amax[0]) * (1.0f / 7.0f);
    float4 a = x[2 * i], c = x[2 * i + 1];
    qx[i] = q8(a.x, s) | q8(a.y, s) << 8 | q8(a.z, s) << 16 |
            q8(a.w, s) << 24 | q8(c.x, s) << 32 | q8(c.y, s) << 40 |
            q8(c.z, s) << 48 | q8(c.w, s) << 56;
  } else if (bid < XB8 + WB8) {
    int i = (bid - XB8) * 256 + tid;
    unsigned long long v = 0ull;
    if (i < N_VOCAB * (D_K / 8)) {
      float s = __uint_as_float(amax[1]) * (1.0f / 7.0f);
      float4 a = Wp[2 * i], c = Wp[2 * i + 1];
      v = q8(a.x, s) | q8(a.y, s) << 8 | q8(a.z, s) << 16 | q8(a.w, s) << 24 |
          q8(c.x, s) << 32 | q8(c.y, s) << 40 | q8(c.z, s) << 48 |
          q8(c.w, s) << 56;
    }
    qw[i] = v;
  } else {
    int i = (bid - (XB8 + WB8)) * 256 + tid;
    if (i < N_PAD) {
      float v = 0.f;
      if (i < N_VOCAB) {
        float sb = (__uint_as_float(amax[0]) * (1.0f / 7.0f)) *
                   (__uint_as_float(amax[1]) * (1.0f / 7.0f));
        v = rintf(b[i] / sb) * sb;
      }
      bq[i] = v;
    }
  }
}

// ---------------- int8 GEMM + fused softmax partials ----------------
// R7 skeleton: 128x128 tile, 4 waves (2x2 of 64x64), BK=64 bytes.
// A double-buffered (16 KB), B in a 4-SLOT ring (32 KB) issued 3 K-steps
// ahead; steady-state barrier wait = counted vmcnt(2) (B(kt+3) stays in
// flight across the barrier; never drained mid-loop). Ring WAR safe: the
// slot written at iter kt is the one read at kt-1 (barrier-protected).
// 8-start XOR swizzle (0 conflicts, verified R5). mfma_i32_16x16x64_i8.
// XCD-bijective grid; on-the-fly epilogue (no lg[] array -> fewer VGPRs).
__global__ __launch_bounds__(256, 4) void gemm_kernel(
    const signed char* __restrict__ qx,   // [2048][1024]
    const signed char* __restrict__ qw,   // [50304][1024]
    const float* __restrict__ bq,         // [50304]
    const unsigned* __restrict__ amax,
    float* __restrict__ outp,             // [2048][50257]
    float* __restrict__ pmax,             // [2048][NB]
    float* __restrict__ psum)             // [2048][NB]
{
  constexpr int BK = 64;
  constexpr int NT = D_K / BK;  // 16
  __shared__ __align__(16) signed char sA[2][128 * BK];  // 16 KB
  __shared__ __align__(16) signed char sB[4][128 * BK];  // 32 KB

  const int tid = threadIdx.x;
  const int l = tid & 63;
  const int w = tid >> 6;
  const int wr = w >> 1, wc = w & 1;

  const int bid = blockIdx.x;
  const int vb = (bid & 7) * PER_XCD + (bid >> 3);
  const int nb = vb >> 4;          // 0..392
  const int m0 = (vb & 15) * 128;
  const int n0 = nb * 128;

  const float sx = __uint_as_float(amax[0]) * (1.0f / 7.0f);
  const float sw = __uint_as_float(amax[1]) * (1.0f / 7.0f);
  const float scale = sx * sw;

  i32x4 acc[4][4] = {};

  const int srow = l >> 2;
  const int scol = ((l & 3) ^ ((l >> 3) & 3)) * 16;

  auto stageA = [&](int buf, int kt) {
    int k0 = kt * BK;
#pragma unroll
    for (int i = 0; i < 2; ++i) {
      int c = w * 2 + i;
      int row = c * 16 + srow;
      async_copy16(qx + (size_t)(m0 + row) * D_K + k0 + scol,
                   &sA[buf][c * 1024]);
    }
  };
  auto stageB = [&](int buf, int kt) {
    int k0 = kt * BK;
#pragma unroll
    for (int i = 0; i < 2; ++i) {
      int c = w * 2 + i;
      int row = c * 16 + srow;
      async_copy16(qw + (size_t)(n0 + row) * D_K + k0 + scol,
                   &sB[buf][c * 1024]);
    }
  };

  // prologue: A0; B0,B1,B2 in flight; retire A0,B0 (vmcnt(4))
  stageA(0, 0);
  stageB(0, 0);
  stageB(1, 1);
  stageB(2, 2);
  asm volatile("s_waitcnt vmcnt(4)" ::: "memory");
  __builtin_amdgcn_s_barrier();
  __builtin_amdgcn_sched_barrier(0);

#pragma unroll
  for (int kt = 0; kt < NT; ++kt) {
    const int ca = kt & 1;
    const int cb = kt & 3;

    i32x4 af[4], bfr[4];
#pragma unroll
    for (int mi = 0; mi < 4; ++mi) {
      int row = wr * 64 + mi * 16 + (l & 15);
      int kb = ((l >> 4) ^ ((row >> 1) & 3)) * 16;
      af[mi] = *(const i32x4*)&sA[ca][row * BK + kb];
    }
#pragma unroll
    for (int ni = 0; ni < 4; ++ni) {
      int row = wc * 64 + ni * 16 + (l & 15);
      int kb = ((l >> 4) ^ ((row >> 1) & 3)) * 16;
      bfr[ni] = *(const i32x4*)&sB[cb][row * BK + kb];
    }

    // prefetch: A one step ahead, B THREE steps ahead
    if (kt + 1 < NT) stageA(ca ^ 1, kt + 1);
    if (kt + 3 < NT) stageB((kt + 3) & 3, kt + 3);

    __builtin_amdgcn_s_setprio(1);
#pragma unroll
    for (int mi = 0; mi < 4; ++mi)
#pragma unroll
      for (int ni = 0; ni < 4; ++ni)
        acc[mi][ni] = __builtin_amdgcn_mfma_i32_16x16x64_i8(
            af[mi], bfr[ni], acc[mi][ni], 0, 0, 0);
    __builtin_amdgcn_s_setprio(0);
    __builtin_amdgcn_sched_barrier(0);

    if (kt + 1 < NT) {
      // need A(kt+1), B(kt+1) done; B(kt+3)'s 2 loads stay in flight
      if (kt + 3 < NT)
        asm volatile("s_waitcnt vmcnt(2)" ::: "memory");
      else
        asm volatile("s_waitcnt vmcnt(0)" ::: "memory");
      __builtin_amdgcn_s_barrier();
      __builtin_amdgcn_sched_barrier(0);
    }
  }

  // ---- epilogue: scale+bias ON THE FLY (no lg array -> fewer VGPRs) ----
  bool valid[4];
  float bb[4];
#pragma unroll
  for (int ni = 0; ni < 4; ++ni) {
    int col = n0 + wc * 64 + ni * 16 + (l & 15);
    valid[ni] = (col < N_VOCAB);
    bb[ni] = valid[ni] ? bq[col] : 0.f;
  }
#define LGT(mi, ni, r) ((float)acc[mi][ni][r] * scale + bb[ni])

  // ---- fused softmax partials (overlay dead sB; barrier first) ----
  __syncthreads();
  float* redMax = (float*)&sB[0][0];  // [128][2]
  float* redSum = redMax + 256;       // [128][2]

  float gm[4][4];
#pragma unroll
  for (int mi = 0; mi < 4; ++mi)
#pragma unroll
    for (int r = 0; r < 4; ++r) {
      float mval = -3.4e38f;
#pragma unroll
      for (int ni = 0; ni < 4; ++ni)
        if (valid[ni]) mval = fmaxf(mval, LGT(mi, ni, r));
#pragma unroll
      for (int off = 1; off < 16; off <<= 1)
        mval = fmaxf(mval, __shfl_xor(mval, off));
      if ((l & 15) == 0)
        redMax[(wr * 64 + mi * 16 + (l >> 4) * 4 + r) * 2 + wc] = mval;
    }
  __syncthreads();

#pragma unroll
  for (int mi = 0; mi < 4; ++mi)
#pragma unroll
    for (int r = 0; r < 4; ++r) {
      int rl = wr * 64 + mi * 16 + (l >> 4) * 4 + r;
      float gmax = fmaxf(redMax[rl * 2 + 0], redMax[rl * 2 + 1]);
      float s = 0.f;
#pragma unroll
      for (int ni = 0; ni < 4; ++ni)
        if (valid[ni]) s += __expf(LGT(mi, ni, r) - gmax);
#pragma unroll
      for (int off = 1; off < 16; off <<= 1)
        s += __shfl_xor(s, off);
      if ((l & 15) == 0) redSum[rl * 2 + wc] = s;
      gm[mi][r] = gmax;
    }
  __syncthreads();

  if (wc == 0 && (l & 15) == 0) {
#pragma unroll
    for (int mi = 0; mi < 4; ++mi)
#pragma unroll
      for (int r = 0; r < 4; ++r) {
        int rl = wr * 64 + mi * 16 + (l >> 4) * 4 + r;
        int rowg = m0 + rl;
        pmax[(size_t)rowg * NB + nb] = gm[mi][r];
        psum[(size_t)rowg * NB + nb] = redSum[rl * 2 + 0] + redSum[rl * 2 + 1];
      }
  }

  // ---- direct logit store, row-grouped ----
#pragma unroll
  for (int mi = 0; mi < 4; ++mi)
#pragma unroll
    for (int r = 0; r < 4; ++r) {
      int rowg = m0 + wr * 64 + mi * 16 + (l >> 4) * 4 + r;
      size_t rb = (size_t)rowg * N_VOCAB;
#pragma unroll
      for (int ni = 0; ni < 4; ++ni) {
        if (valid[ni]) {
          int col = n0 + wc * 64 + ni * 16 + (l & 15);
          outp[rb + col] = LGT(mi, ni, r);
        }
      }
    }
#undef LGT
}

// ---------------- merged: per-row logZ + subtract (4 blocks per row) --------
__global__ __launch_bounds__(256) void logz_sub_kernel(
    const float* __restrict__ pmax, const float* __restrict__ psum,
    float* __restrict__ out) {
  const int row = blockIdx.x >> 2;
  const int part = blockIdx.x & 3;
  const float* pm = pmax + (size_t)row * NB;
  const float* ps = psum + (size_t)row * NB;
  const int tid = threadIdx.x;
  __shared__ float red[9];

  float m = -3.4e38f;
  for (int i = tid; i < NB; i += 256) m = fmaxf(m, pm[i]);
#pragma unroll
  for (int off = 32; off; off >>= 1) m = fmaxf(m, __shfl_xor(m, off));
  if ((tid & 63) == 0) red[tid >> 6] = m;
  __syncthreads();
  m = fmaxf(fmaxf(red[0], red[1]), fmaxf(red[2], red[3]));

  float s = 0.f;
  for (int i = tid; i < NB; i += 256) s += ps[i] * __expf(pm[i] - m);
#pragma unroll
  for (int off = 32; off; off >>= 1) s += __shfl_xor(s, off);
  if ((tid & 63) == 0) red[4 + (tid >> 6)] = s;
  __syncthreads();
  if (tid == 0) {
    s = red[4] + red[5] + red[6] + red[7];
    red[8] = m + __logf(s);
  }
  __syncthreads();
  const float lz = red[8];

  const size_t base = (size_t)row * N_VOCAB;
  const int a = (4 - (row & 3)) & 3;  // head scalars to align to 16B
  const int n4 = (N_VOCAB - a) >> 2;  // aligned float4 count
  const int p4 = (n4 + 3) >> 2;       // per-part float4s
  const int i0 = part * p4;
  const int i1 = min(n4, i0 + p4);
  float4* p = (float4*)(out + base + a);
  for (int i = i0 + tid; i < i1; i += 256) {
    float4 v = p[i];
    v.x -= lz; v.y -= lz; v.z -= lz; v.w -= lz;
    p[i] = v;
  }
  if (part == 0) {
    if (tid < a) out[base + tid] -= lz;
  } else if (part == 3) {
    const int done = a + n4 * 4;
    if (tid < N_VOCAB - done) out[base + done + tid] -= lz;
  }
}

extern "C" void kernel_launch(void* const* d_in, const int* in_sizes, int n_in,
                              void* d_out, int out_size, void* d_ws,
                              size_t ws_size, hipStream_t stream) {
  const float* x = (const float*)d_in[0];
  const float* W = (const float*)d_in[1];
  const float* b = (const float*)d_in[2];
  float* out = (float*)d_out;

  char* ws = (char*)d_ws;
  unsigned* amax = (unsigned*)ws;                       // 8 B
  float* bq = (float*)(ws + 4096);                      // 201 KB
  float* pmax = (float*)(ws + (2ull << 20));            // 3.22 MB
  float* psum = (float*)(ws + (6ull << 20));            // 3.22 MB
  signed char* qx = (signed char*)(ws + (10ull << 20)); // 2 MB
  signed char* qw = (signed char*)(ws + (14ull << 20)); // 51.5 MB

  hipMemsetAsync(amax, 0, 8, stream);

  const int nx4 = (M_ROWS * D_K) / 4;   // 524288
  const int nw4 = (N_VOCAB * D_K) / 4;  // 12865792

  absmax2_kernel<<<512 + 4096, 256, 0, stream>>>((const float4*)x, nx4,
                                                 (const float4*)W, nw4, amax);

  quant_kernel<<<XB8 + WB8 + 197, 256, 0, stream>>>(
      (const float4*)x, (const float4*)W, b, (unsigned long long*)qx,
      (unsigned long long*)qw, bq, amax);

  gemm_kernel<<<GEMM_BLOCKS, 256, 0, stream>>>(qx, qw, bq, amax, out, pmax,
                                               psum);

  logz_sub_kernel<<<M_ROWS * 4, 256, 0, stream>>>(pmax, psum, out);
}

// Round 13
// 533.419 us; speedup vs baseline: 1.3242x; 1.1578x over previous
//
#include <hip/hip_runtime.h>
#include <hip/hip_bf16.h>

#define N_VOCAB 50257
#define NB      393     // n-block columns
#define N_PAD   50304   // 393 * 128
#define D_K     1024
#define M_ROWS  2048
#define GEMM_BLOCKS (NB * 16)       // 6288 = 8 * 786
#define PER_XCD     (GEMM_BLOCKS/8) // 786

typedef __attribute__((ext_vector_type(4))) int i32x4;

__device__ inline void async_copy16(const void* g, void* l) {
  auto* gp = (const __attribute__((address_space(1))) unsigned int*)g;
  auto* lp = (__attribute__((address_space(3))) unsigned int*)l;
  __builtin_amdgcn_global_load_lds(gp, lp, 16, 0, 0);
}

__device__ inline unsigned long long q8(float v, float s) {
  float q = fminf(fmaxf(rintf(v / s), -8.f), 7.f);
  return (unsigned long long)(unsigned char)(signed char)(int)q;
}

// ---------------- fused absmax (x -> amax[0], W -> amax[1]) ----------------
__global__ __launch_bounds__(256) void absmax2_kernel(
    const float4* __restrict__ x, int nx4, const float4* __restrict__ Wp,
    int nw4, unsigned* __restrict__ amax) {
  const bool isx = blockIdx.x < 512;
  const float4* p = isx ? x : Wp;
  const int n4 = isx ? nx4 : nw4;
  const int b0 = isx ? blockIdx.x : blockIdx.x - 512;
  const int nb = isx ? 512 : (gridDim.x - 512);
  float m = 0.f;
  for (int i = b0 * blockDim.x + threadIdx.x; i < n4; i += nb * blockDim.x) {
    float4 v = p[i];
    m = fmaxf(m, fmaxf(fmaxf(fabsf(v.x), fabsf(v.y)),
                       fmaxf(fabsf(v.z), fabsf(v.w))));
  }
#pragma unroll
  for (int off = 32; off; off >>= 1) m = fmaxf(m, __shfl_xor(m, off));
  __shared__ float red[4];
  int tid = threadIdx.x;
  if ((tid & 63) == 0) red[tid >> 6] = m;
  __syncthreads();
  if (tid == 0) {
    m = fmaxf(fmaxf(red[0], red[1]), fmaxf(red[2], red[3]));
    atomicMax(&amax[isx ? 0 : 1], __float_as_uint(m));
  }
}

// ---------------- fused quantize x, W (8 elems/thread), bias ----------------
#define XB8  1024   // x blocks: 2048*1024/8/256
#define WB8  25152  // W blocks: 50304*1024/8/256
__global__ __launch_bounds__(256) void quant_kernel(
    const float4* __restrict__ x, const float4* __restrict__ Wp,
    const float* __restrict__ b, unsigned long long* __restrict__ qx,
    unsigned long long* __restrict__ qw, float* __restrict__ bq,
    const unsigned* __restrict__ amax) {
  const int bid = blockIdx.x;
  const int tid = threadIdx.x;
  if (bid < XB8) {
    int i = bid * 256 + tid;
    float s = __uint_as_float(amax[0]) * (1.0f / 7.0f);
    float4 a = x[2 * i], c = x[2 * i + 1];
    qx[i] = q8(a.x, s) | q8(a.y, s) << 8 | q8(a.z, s) << 16 |
            q8(a.w, s) << 24 | q8(c.x, s) << 32 | q8(c.y, s) << 40 |
            q8(c.z, s) << 48 | q8(c.w, s) << 56;
  } else if (bid < XB8 + WB8) {
    int i = (bid - XB8) * 256 + tid;
    unsigned long long v = 0ull;
    if (i < N_VOCAB * (D_K / 8)) {
      float s = __uint_as_float(amax[1]) * (1.0f / 7.0f);
      float4 a = Wp[2 * i], c = Wp[2 * i + 1];
      v = q8(a.x, s) | q8(a.y, s) << 8 | q8(a.z, s) << 16 | q8(a.w, s) << 24 |
          q8(c.x, s) << 32 | q8(c.y, s) << 40 | q8(c.z, s) << 48 |
          q8(c.w, s) << 56;
    }
    qw[i] = v;
  } else {
    int i = (bid - (XB8 + WB8)) * 256 + tid;
    if (i < N_PAD) {
      float v = 0.f;
      if (i < N_VOCAB) {
        float sb = (__uint_as_float(amax[0]) * (1.0f / 7.0f)) *
                   (__uint_as_float(amax[1]) * (1.0f / 7.0f));
        v = rintf(b[i] / sb) * sb;
      }
      bq[i] = v;
    }
  }
}

// ---------------- int8 GEMM + fused softmax partials (R7 exact) ----------
// 128x128 tile, 4 waves (2x2 of 64x64), BK=64 bytes. A double-buffered
// (16 KB); B triple-ring (24 KB) issued 2 K-steps ahead. Counted vmcnt(2)
// (never 0 mid-loop) + raw s_barrier. LDS 40KB -> 4 blocks/CU. 8-start XOR
// swizzle (0 conflicts). mfma_i32_16x16x64_i8. XCD-bijective grid.
__global__ __launch_bounds__(256, 4) void gemm_kernel(
    const signed char* __restrict__ qx,   // [2048][1024]
    const signed char* __restrict__ qw,   // [50304][1024]
    const float* __restrict__ bq,         // [50304]
    const unsigned* __restrict__ amax,
    float* __restrict__ outp,             // [2048][50257]
    float* __restrict__ pmax,             // [2048][NB]
    float* __restrict__ psum)             // [2048][NB]
{
  constexpr int BK = 64;
  constexpr int NT = D_K / BK;  // 16
  __shared__ __align__(16) signed char sA[2][128 * BK];  // 16 KB
  __shared__ __align__(16) signed char sB[3][128 * BK];  // 24 KB

  const int tid = threadIdx.x;
  const int l = tid & 63;
  const int w = tid >> 6;
  const int wr = w >> 1, wc = w & 1;

  const int bid = blockIdx.x;
  const int vb = (bid & 7) * PER_XCD + (bid >> 3);
  const int nb = vb >> 4;          // 0..392
  const int m0 = (vb & 15) * 128;
  const int n0 = nb * 128;

  const float sx = __uint_as_float(amax[0]) * (1.0f / 7.0f);
  const float sw = __uint_as_float(amax[1]) * (1.0f / 7.0f);
  const float scale = sx * sw;

  i32x4 acc[4][4] = {};

  const int srow = l >> 2;
  const int scol = ((l & 3) ^ ((l >> 3) & 3)) * 16;

  auto stageA = [&](int buf, int kt) {
    int k0 = kt * BK;
#pragma unroll
    for (int i = 0; i < 2; ++i) {
      int c = w * 2 + i;
      int row = c * 16 + srow;
      async_copy16(qx + (size_t)(m0 + row) * D_K + k0 + scol,
                   &sA[buf][c * 1024]);
    }
  };
  auto stageB = [&](int buf, int kt) {
    int k0 = kt * BK;
#pragma unroll
    for (int i = 0; i < 2; ++i) {
      int c = w * 2 + i;
      int row = c * 16 + srow;
      async_copy16(qw + (size_t)(n0 + row) * D_K + k0 + scol,
                   &sB[buf][c * 1024]);
    }
  };

  // prologue: A0, B0, B1 in flight; wait A0+B0 (B1 stays outstanding)
  stageA(0, 0);
  stageB(0, 0);
  stageB(1, 1);
  asm volatile("s_waitcnt vmcnt(2)" ::: "memory");
  __builtin_amdgcn_s_barrier();
  __builtin_amdgcn_sched_barrier(0);

#pragma unroll
  for (int kt = 0; kt < NT; ++kt) {
    const int ca = kt & 1;
    const int cb = kt % 3;

    i32x4 af[4], bfr[4];
#pragma unroll
    for (int mi = 0; mi < 4; ++mi) {
      int row = wr * 64 + mi * 16 + (l & 15);
      int kb = ((l >> 4) ^ ((row >> 1) & 3)) * 16;
      af[mi] = *(const i32x4*)&sA[ca][row * BK + kb];
    }
#pragma unroll
    for (int ni = 0; ni < 4; ++ni) {
      int row = wc * 64 + ni * 16 + (l & 15);
      int kb = ((l >> 4) ^ ((row >> 1) & 3)) * 16;
      bfr[ni] = *(const i32x4*)&sB[cb][row * BK + kb];
    }

    // prefetch: A one step ahead, B two steps ahead
    if (kt + 1 < NT) stageA(ca ^ 1, kt + 1);
    if (kt + 2 < NT) stageB((kt + 2) % 3, kt + 2);

    __builtin_amdgcn_s_setprio(1);
#pragma unroll
    for (int mi = 0; mi < 4; ++mi)
#pragma unroll
      for (int ni = 0; ni < 4; ++ni)
        acc[mi][ni] = __builtin_amdgcn_mfma_i32_16x16x64_i8(
            af[mi], bfr[ni], acc[mi][ni], 0, 0, 0);
    __builtin_amdgcn_s_setprio(0);
    __builtin_amdgcn_sched_barrier(0);

    if (kt + 1 < NT) {
      // need A(kt+1), B(kt+1) done; B(kt+2)'s 2 loads may stay in flight
      if (kt + 2 < NT)
        asm volatile("s_waitcnt vmcnt(2)" ::: "memory");
      else
        asm volatile("s_waitcnt vmcnt(0)" ::: "memory");
      __builtin_amdgcn_s_barrier();
      __builtin_amdgcn_sched_barrier(0);
    }
  }

  // ---- scale + bias ----
  bool valid[4];
  float bb[4];
#pragma unroll
  for (int ni = 0; ni < 4; ++ni) {
    int col = n0 + wc * 64 + ni * 16 + (l & 15);
    valid[ni] = (col < N_VOCAB);
    bb[ni] = valid[ni] ? bq[col] : 0.f;
  }
  float lg[4][4][4];
#pragma unroll
  for (int mi = 0; mi < 4; ++mi)
#pragma unroll
    for (int ni = 0; ni < 4; ++ni)
#pragma unroll
      for (int r = 0; r < 4; ++r)
        lg[mi][ni][r] = (float)acc[mi][ni][r] * scale + bb[ni];

  // ---- fused softmax partials (overlay dead sB; barrier first) ----
  __syncthreads();  // all waves done reading LDS before overlay writes
  float* redMax = (float*)&sB[0][0];  // [128][2]
  float* redSum = redMax + 256;       // [128][2]

  float rmax[4][4];
#pragma unroll
  for (int mi = 0; mi < 4; ++mi)
#pragma unroll
    for (int r = 0; r < 4; ++r) {
      float mval = -3.4e38f;
#pragma unroll
      for (int ni = 0; ni < 4; ++ni)
        if (valid[ni]) mval = fmaxf(mval, lg[mi][ni][r]);
#pragma unroll
      for (int off = 1; off < 16; off <<= 1)
        mval = fmaxf(mval, __shfl_xor(mval, off));
      rmax[mi][r] = mval;
      if ((l & 15) == 0)
        redMax[(wr * 64 + mi * 16 + (l >> 4) * 4 + r) * 2 + wc] = mval;
    }
  __syncthreads();

#pragma unroll
  for (int mi = 0; mi < 4; ++mi)
#pragma unroll
    for (int r = 0; r < 4; ++r) {
      int rl = wr * 64 + mi * 16 + (l >> 4) * 4 + r;
      float gmax = fmaxf(redMax[rl * 2 + 0], redMax[rl * 2 + 1]);
      float s = 0.f;
#pragma unroll
      for (int ni = 0; ni < 4; ++ni)
        if (valid[ni]) s += __expf(lg[mi][ni][r] - gmax);
#pragma unroll
      for (int off = 1; off < 16; off <<= 1)
        s += __shfl_xor(s, off);
      if ((l & 15) == 0) redSum[rl * 2 + wc] = s;
      rmax[mi][r] = gmax;
    }
  __syncthreads();

  if (wc == 0 && (l & 15) == 0) {
#pragma unroll
    for (int mi = 0; mi < 4; ++mi)
#pragma unroll
      for (int r = 0; r < 4; ++r) {
        int rl = wr * 64 + mi * 16 + (l >> 4) * 4 + r;
        int rowg = m0 + rl;
        pmax[(size_t)rowg * NB + nb] = rmax[mi][r];
        psum[(size_t)rowg * NB + nb] = redSum[rl * 2 + 0] + redSum[rl * 2 + 1];
      }
  }

  // ---- direct logit store, row-grouped ----
#pragma unroll
  for (int mi = 0; mi < 4; ++mi)
#pragma unroll
    for (int r = 0; r < 4; ++r) {
      int rowg = m0 + wr * 64 + mi * 16 + (l >> 4) * 4 + r;
      size_t rb = (size_t)rowg * N_VOCAB;
#pragma unroll
      for (int ni = 0; ni < 4; ++ni) {
        if (valid[ni]) {
          int col = n0 + wc * 64 + ni * 16 + (l & 15);
          outp[rb + col] = lg[mi][ni][r];
        }
      }
    }
}

// ---------------- merged: per-row logZ + subtract (4 blocks per row) --------
__global__ __launch_bounds__(256) void logz_sub_kernel(
    const float* __restrict__ pmax, const float* __restrict__ psum,
    float* __restrict__ out) {
  const int row = blockIdx.x >> 2;
  const int part = blockIdx.x & 3;
  const float* pm = pmax + (size_t)row * NB;
  const float* ps = psum + (size_t)row * NB;
  const int tid = threadIdx.x;
  __shared__ float red[9];

  float m = -3.4e38f;
  for (int i = tid; i < NB; i += 256) m = fmaxf(m, pm[i]);
#pragma unroll
  for (int off = 32; off; off >>= 1) m = fmaxf(m, __shfl_xor(m, off));
  if ((tid & 63) == 0) red[tid >> 6] = m;
  __syncthreads();
  m = fmaxf(fmaxf(red[0], red[1]), fmaxf(red[2], red[3]));

  float s = 0.f;
  for (int i = tid; i < NB; i += 256) s += ps[i] * __expf(pm[i] - m);
#pragma unroll
  for (int off = 32; off; off >>= 1) s += __shfl_xor(s, off);
  if ((tid & 63) == 0) red[4 + (tid >> 6)] = s;
  __syncthreads();
  if (tid == 0) {
    s = red[4] + red[5] + red[6] + red[7];
    red[8] = m + __logf(s);
  }
  __syncthreads();
  const float lz = red[8];

  const size_t base = (size_t)row * N_VOCAB;
  const int a = (4 - (row & 3)) & 3;  // head scalars to align to 16B
  const int n4 = (N_VOCAB - a) >> 2;  // aligned float4 count
  const int p4 = (n4 + 3) >> 2;       // per-part float4s
  const int i0 = part * p4;
  const int i1 = min(n4, i0 + p4);
  float4* p = (float4*)(out + base + a);
  for (int i = i0 + tid; i < i1; i += 256) {
    float4 v = p[i];
    v.x -= lz; v.y -= lz; v.z -= lz; v.w -= lz;
    p[i] = v;
  }
  if (part == 0) {
    if (tid < a) out[base + tid] -= lz;
  } else if (part == 3) {
    const int done = a + n4 * 4;
    if (tid < N_VOCAB - done) out[base + done + tid] -= lz;
  }
}

extern "C" void kernel_launch(void* const* d_in, const int* in_sizes, int n_in,
                              void* d_out, int out_size, void* d_ws,
                              size_t ws_size, hipStream_t stream) {
  const float* x = (const float*)d_in[0];
  const float* W = (const float*)d_in[1];
  const float* b = (const float*)d_in[2];
  float* out = (float*)d_out;

  char* ws = (char*)d_ws;
  unsigned* amax = (unsigned*)ws;                       // 8 B
  float* bq = (float*)(ws + 4096);                      // 201 KB
  float* pmax = (float*)(ws + (2ull << 20));            // 3.22 MB
  float* psum = (float*)(ws + (6ull << 20));            // 3.22 MB
  signed char* qx = (signed char*)(ws + (10ull << 20)); // 2 MB
  signed char* qw = (signed char*)(ws + (14ull << 20)); // 51.5 MB

  hipMemsetAsync(amax, 0, 8, stream);

  const int nx4 = (M_ROWS * D_K) / 4;   // 524288
  const int nw4 = (N_VOCAB * D_K) / 4;  // 12865792

  absmax2_kernel<<<512 + 4096, 256, 0, stream>>>((const float4*)x, nx4,
                                                 (const float4*)W, nw4, amax);

  quant_kernel<<<XB8 + WB8 + 197, 256, 0, stream>>>(
      (const float4*)x, (const float4*)W, b, (unsigned long long*)qx,
      (unsigned long long*)qw, bq, amax);

  gemm_kernel<<<GEMM_BLOCKS, 256, 0, stream>>>(qx, qw, bq, amax, out, pmax,
                                               psum);

  logz_sub_kernel<<<M_ROWS * 4, 256, 0, stream>>>(pmax, psum, out);
}